// Round 2
// baseline (1010.159 us; speedup 1.0000x reference)
//
#include <hip/hip_runtime.h>
#include <stdint.h>
#include <math.h>

// ---------------------------------------------------------------------------
// HippocampalFastWeight on MI355X (gfx950)
// B=8, T=2048, D=512, N=2048, K_CA3=64
// Runtime batch-chunking: Bc batches per chunk, sized to fit ws_size.
// Per chunk:
//   gemm1: h = relu(x @ down_W^T)            bf16 out (regA)
//   topk1: S = l2norm(kwta(h,64)) dense bf16 (regB)       [exact 16-bit radix]
//   transpose: ST[n][t] = S[t][n]            (regA, over dead h)
//   gemmW: W = shift(ST) @ ST^T, diag=0      bf16 (regC)  [shift in registers]
//   gemmS: succ = relu(S @ W^T)              bf16 (regA, over dead ST)
//   topk2: sparse (idx,val) of l2norm(kwta(succ,64))
//   gate:  g = sigmoid(x @ gate_W^T + b)     fp32 (regB, over dead S)
//   final: out = x + g * sum_j val_j * upT[idx_j][:]
// ---------------------------------------------------------------------------

typedef __attribute__((ext_vector_type(8))) short bf16x8;
typedef __attribute__((ext_vector_type(8))) unsigned short u16x8;
typedef __attribute__((ext_vector_type(4))) float f32x4;

__device__ __forceinline__ uint16_t f2bf(float f) {
  uint32_t u = __float_as_uint(f);
  uint32_t r = u + 0x7FFFu + ((u >> 16) & 1u);
  return (uint16_t)(r >> 16);
}
__device__ __forceinline__ float bf2f(unsigned u) {
  return __uint_as_float(u << 16);
}

// ------------------------------- cast --------------------------------------
__global__ __launch_bounds__(256) void cast_f32_bf16_k(
    const float* __restrict__ s, uint16_t* __restrict__ d, long long n) {
  long long i = (long long)blockIdx.x * 256 + threadIdx.x;
  long long stride = (long long)gridDim.x * 256;
  for (; i < n; i += stride) d[i] = f2bf(s[i]);
}

// --------------------- transpose up_W (D x N -> N x D) ---------------------
__global__ __launch_bounds__(256) void transpose_upw_k(
    const float* __restrict__ src, float* __restrict__ dst, int D, int N) {
  __shared__ float t[32][33];
  int n0 = blockIdx.x * 32, d0 = blockIdx.y * 32;
  int lx = threadIdx.x & 31, ly = threadIdx.x >> 5;  // 32 x 8
#pragma unroll
  for (int r = 0; r < 4; ++r) {
    int d = d0 + ly + r * 8;
    t[ly + r * 8][lx] = src[(long long)d * N + n0 + lx];
  }
  __syncthreads();
#pragma unroll
  for (int r = 0; r < 4; ++r) {
    int n = n0 + ly + r * 8;
    dst[(long long)n * D + d0 + lx] = t[lx][ly + r * 8];
  }
}

// ------------------------------- GEMM --------------------------------------
// C[M,N] = A[M,K] * B[N,K]^T (bf16 in, fp32 accum). 128x128 tile, BK=32.
// SHIFT_A: A[i][k] := A_mem[i][k+1], zero at k+1==K (Hebbian t+1 shift).
#define EPI_RELU_BF16 0
#define EPI_DIAG0 1
#define EPI_SIG 2

template <int EPI, int SHIFT_A>
__global__ __launch_bounds__(256) void gemm_bt_k(
    const uint16_t* __restrict__ A, const uint16_t* __restrict__ B,
    void* __restrict__ Cv, const float* __restrict__ bias,
    int M, int N, int K, long long sA, long long sB, long long sC) {
  __shared__ __align__(16) uint16_t As[128 * 32];
  __shared__ __align__(16) uint16_t Bs[128 * 32];
  const int b = blockIdx.z;
  const uint16_t* Ab = A + (long long)b * sA;
  const uint16_t* Bb = B + (long long)b * sB;
  const int tid = threadIdx.x;
  const int lane = tid & 63;
  const int wave = tid >> 6;
  const int m0 = blockIdx.x * 128;
  const int n0 = blockIdx.y * 128;
  const int wm = (wave & 1) * 64;
  const int wn = (wave >> 1) * 64;
  const int quad = lane >> 4;
  const int l16 = lane & 15;

  f32x4 acc[4][4];
#pragma unroll
  for (int i = 0; i < 4; ++i)
#pragma unroll
    for (int j = 0; j < 4; ++j) acc[i][j] = (f32x4){0.f, 0.f, 0.f, 0.f};

  const int r0 = tid >> 2;  // 0..63
  const int seg = tid & 3;  // 16B segment of 64B k-row

  for (int k0 = 0; k0 < K; k0 += 32) {
    const int kidx = k0 + seg * 8;
#pragma unroll
    for (int it = 0; it < 2; ++it) {
      int row = it * 64 + r0;
      const uint16_t* ap = Ab + (long long)(m0 + row) * K + kidx;
      u16x8 av = *(const u16x8*)ap;
      if (SHIFT_A) {
        u16x8 sh;
#pragma unroll
        for (int q = 0; q < 7; ++q) sh[q] = av[q + 1];
        sh[7] = (kidx + 8 < K) ? ap[8] : (unsigned short)0;
        av = sh;
      }
      u16x8 bv = *(const u16x8*)(Bb + (long long)(n0 + row) * K + kidx);
      *(u16x8*)(&As[row * 32 + seg * 8]) = av;
      *(u16x8*)(&Bs[row * 32 + seg * 8]) = bv;
    }
    __syncthreads();
    bf16x8 af[4], bfr[4];
#pragma unroll
    for (int i = 0; i < 4; ++i)
      af[i] = *(const bf16x8*)(&As[(wm + i * 16 + l16) * 32 + quad * 8]);
#pragma unroll
    for (int j = 0; j < 4; ++j)
      bfr[j] = *(const bf16x8*)(&Bs[(wn + j * 16 + l16) * 32 + quad * 8]);
#pragma unroll
    for (int i = 0; i < 4; ++i)
#pragma unroll
      for (int j = 0; j < 4; ++j)
        acc[i][j] = __builtin_amdgcn_mfma_f32_16x16x32_bf16(af[i], bfr[j], acc[i][j], 0, 0, 0);
    __syncthreads();
  }

  // epilogue: C[m0+wm+i*16+quad*4+r][n0+wn+j*16+l16]
#pragma unroll
  for (int i = 0; i < 4; ++i) {
#pragma unroll
    for (int j = 0; j < 4; ++j) {
#pragma unroll
      for (int r = 0; r < 4; ++r) {
        int row = m0 + wm + i * 16 + quad * 4 + r;
        int col = n0 + wn + j * 16 + l16;
        float v = acc[i][j][r];
        if (EPI == EPI_RELU_BF16) {
          uint16_t* C = (uint16_t*)Cv + (long long)b * sC;
          C[(long long)row * N + col] = f2bf(v > 0.f ? v : 0.f);
        } else if (EPI == EPI_DIAG0) {
          uint16_t* C = (uint16_t*)Cv + (long long)b * sC;
          C[(long long)row * N + col] = (row == col) ? (uint16_t)0 : f2bf(v);
        } else {
          float* C = (float*)Cv + (long long)b * sC;
          float z = v + bias[col];
          C[(long long)row * N + col] = 1.f / (1.f + __expf(-z));
        }
      }
    }
  }
}

// -------------------- transpose S (TxN) -> ST (NxT), bf16 -------------------
__global__ __launch_bounds__(256) void transpose_k(
    const uint16_t* __restrict__ S, uint16_t* __restrict__ ST, int T, int N) {
  __shared__ uint16_t tile[64][65];
  int t0 = blockIdx.x * 64, n0 = blockIdx.y * 64, b = blockIdx.z;
  const uint16_t* Sb = S + (long long)b * T * N;
  uint16_t* STb = ST + (long long)b * N * T;
  for (int idx = threadIdx.x; idx < 64 * 64; idx += 256) {
    int t = idx >> 6, n = idx & 63;
    tile[t][n] = Sb[(long long)(t0 + t) * N + n0 + n];
  }
  __syncthreads();
  for (int idx = threadIdx.x; idx < 64 * 64; idx += 256) {
    int n = idx >> 6, t = idx & 63;
    STb[(long long)(n0 + n) * T + t0 + t] = tile[t][n];
  }
}

// -------------- exact top-64 + L2 normalize, bf16 keys (N=2048) ------------
// 2-pass radix over the 16-bit bf16 pattern (values >= 0 so uint order ==
// float order). Ties filled lowest-index-first (matches lax.top_k).
template <int SPARSE>
__global__ __launch_bounds__(256) void topk_bf16_k(
    const uint16_t* __restrict__ H, uint16_t* __restrict__ Sout,
    int* __restrict__ idxo, float* __restrict__ valo) {
  const long long row = blockIdx.x;
  const uint16_t* h = H + row * 2048;
  const int tid = threadIdx.x;
  u16x8 v = *(const u16x8*)(h + tid * 8);  // contiguous 8 keys per thread

  __shared__ int hist[256];
  __shared__ int scan[256];
  __shared__ int sel_bin, sel_need;
  __shared__ int cgt_sh;
  __shared__ float ss_sh;
  __shared__ int app_sh;

  // pass 1: high byte
  hist[tid] = 0;
  if (tid == 0) { cgt_sh = 0; ss_sh = 0.f; app_sh = 0; }
  __syncthreads();
#pragma unroll
  for (int i = 0; i < 8; ++i) atomicAdd(&hist[v[i] >> 8], 1);
  __syncthreads();
  scan[tid] = hist[tid];
  __syncthreads();
  for (int o = 1; o < 256; o <<= 1) {
    int x = scan[tid] + ((tid + o < 256) ? scan[tid + o] : 0);
    __syncthreads();
    scan[tid] = x;
    __syncthreads();
  }
  if (scan[tid] >= 64 && (tid == 255 || scan[tid + 1] < 64)) {
    sel_bin = tid;
    sel_need = 64 - ((tid == 255) ? 0 : scan[tid + 1]);
  }
  __syncthreads();
  const int b1 = sel_bin;
  const int need1 = sel_need;
  __syncthreads();

  // pass 2: low byte among keys with high byte == b1
  hist[tid] = 0;
  __syncthreads();
#pragma unroll
  for (int i = 0; i < 8; ++i)
    if ((int)(v[i] >> 8) == b1) atomicAdd(&hist[v[i] & 255], 1);
  __syncthreads();
  scan[tid] = hist[tid];
  __syncthreads();
  for (int o = 1; o < 256; o <<= 1) {
    int x = scan[tid] + ((tid + o < 256) ? scan[tid + o] : 0);
    __syncthreads();
    scan[tid] = x;
    __syncthreads();
  }
  if (scan[tid] >= need1 && (tid == 255 || scan[tid + 1] < need1)) sel_bin = tid;
  __syncthreads();
  const unsigned thresh = ((unsigned)b1 << 8) | (unsigned)sel_bin;
  const float thf = bf2f(thresh);

  // counts: strictly-greater (always kept) and ties
  int cgt = 0, ctie = 0;
  float ssq = 0.f;
#pragma unroll
  for (int i = 0; i < 8; ++i) {
    unsigned u = v[i];
    if (u > thresh) { cgt++; float f = bf2f(u); ssq += f * f; }
    else if (u == thresh) ctie++;
  }
  atomicAdd(&cgt_sh, cgt);
  atomicAdd(&ss_sh, ssq);
  __syncthreads();
  // exclusive prefix of tie counts by tid (index-ordered tie break)
  scan[tid] = ctie;
  __syncthreads();
  for (int o = 1; o < 256; o <<= 1) {
    int x = scan[tid] + ((tid >= o) ? scan[tid - o] : 0);
    __syncthreads();
    scan[tid] = x;
    __syncthreads();
  }
  const int tie_base = scan[tid] - ctie;
  const int r = 64 - cgt_sh;  // tie copies to take (>=1)
  const float sumsq = ss_sh + (float)r * thf * thf;
  const float inv = 1.f / fmaxf(sqrtf(sumsq), 1e-10f);

  if (SPARSE) {
    int tseen = 0;
#pragma unroll
    for (int i = 0; i < 8; ++i) {
      unsigned u = v[i];
      bool sel = (u > thresh);
      if (u == thresh) { sel = (tie_base + tseen) < r; tseen++; }
      if (sel) {
        int p = atomicAdd(&app_sh, 1);  // exactly 64 total claims
        idxo[row * 64 + p] = tid * 8 + i;
        valo[row * 64 + p] = bf2f(u) * inv;
      }
    }
  } else {
    u16x8 o16;
    int tseen = 0;
#pragma unroll
    for (int i = 0; i < 8; ++i) {
      unsigned u = v[i];
      bool sel = (u > thresh);
      if (u == thresh) { sel = (tie_base + tseen) < r; tseen++; }
      o16[i] = sel ? (unsigned short)f2bf(bf2f(u) * inv) : (unsigned short)0;
    }
    *(u16x8*)(Sout + row * 2048 + tid * 8) = o16;
  }
}

// ------------------------------- final -------------------------------------
// out[row,d] = x[row,d] + g[row,d] * sum_j val[j]*upT[idx[j]][d]
__global__ __launch_bounds__(128) void final_k(
    const float* __restrict__ x, const float* __restrict__ g,
    const float* __restrict__ upT, const int* __restrict__ idxo,
    const float* __restrict__ valo, float* __restrict__ out, int D) {
  long long row = blockIdx.x;
  __shared__ int sidx[64];
  __shared__ float sval[64];
  int tid = threadIdx.x;
  if (tid < 64) {
    sidx[tid] = idxo[row * 64 + tid];
    sval[tid] = valo[row * 64 + tid];
  }
  __syncthreads();
  int d = tid * 4;
  float4 a = {0.f, 0.f, 0.f, 0.f};
#pragma unroll 8
  for (int j = 0; j < 64; ++j) {
    float v = sval[j];
    const float4 u = *(const float4*)(upT + (long long)sidx[j] * D + d);
    a.x = fmaf(v, u.x, a.x);
    a.y = fmaf(v, u.y, a.y);
    a.z = fmaf(v, u.z, a.z);
    a.w = fmaf(v, u.w, a.w);
  }
  long long o = row * D + d;
  const float4 xv = *(const float4*)(x + o);
  const float4 gv = *(const float4*)(g + o);
  float4 rr;
  rr.x = xv.x + gv.x * a.x;
  rr.y = xv.y + gv.y * a.y;
  rr.z = xv.z + gv.z * a.z;
  rr.w = xv.w + gv.w * a.w;
  *(float4*)(out + o) = rr;
}

// ---------------------------------------------------------------------------
extern "C" void kernel_launch(void* const* d_in, const int* in_sizes, int n_in,
                              void* d_out, int out_size, void* d_ws, size_t ws_size,
                              hipStream_t stream) {
  const float* x = (const float*)d_in[0];
  const float* downW = (const float*)d_in[1];
  const float* upW = (const float*)d_in[2];
  const float* gateW = (const float*)d_in[3];
  const float* gateB = (const float*)d_in[4];
  float* out = (float*)d_out;

  const int B = 8, T = 2048, D = 512, N = 2048;
  const long long BT = (long long)B * T;
  const long long TN = (long long)T * N;   // 4,194,304
  const long long NN = (long long)N * N;   // 4,194,304
  const long long TD = (long long)T * D;   // 1,048,576

  // fixed buffers
  char* base = (char*)d_ws;
  size_t off = 0;
  auto take = [&](size_t bytes) {
    size_t o = off;
    off += (bytes + 255) & ~(size_t)255;
    return o;
  };
  size_t o_xb = take((size_t)BT * D * 2);   // 16 MiB
  size_t o_dwb = take((size_t)N * D * 2);   // 2 MiB
  size_t o_gwb = take((size_t)D * D * 2);   // 0.5 MiB
  size_t o_upT = take((size_t)N * D * 4);   // 4 MiB
  const size_t fixed = off;
  // per-batch chunk cost: regA + regB + regC + idx2 + val2
  const size_t perb = (size_t)TN * 2 + (size_t)TN * 2 + (size_t)NN * 2 +
                      (size_t)T * 64 * 4 * 2;  // 25 MiB
  int Bc = 1;
  if (ws_size >= fixed + 8 * perb) Bc = 8;
  else if (ws_size >= fixed + 4 * perb) Bc = 4;
  else if (ws_size >= fixed + 2 * perb) Bc = 2;

  uint16_t* xb = (uint16_t*)(base + o_xb);
  uint16_t* dwb = (uint16_t*)(base + o_dwb);
  uint16_t* gwb = (uint16_t*)(base + o_gwb);
  float* upT = (float*)(base + o_upT);
  char* p = base + fixed;
  uint16_t* regA = (uint16_t*)p; p += (size_t)TN * 2 * Bc;  // h -> ST -> succ
  uint16_t* regB = (uint16_t*)p; p += (size_t)TN * 2 * Bc;  // S -> g(fp32)
  uint16_t* regC = (uint16_t*)p; p += (size_t)NN * 2 * Bc;  // W
  int* idx2 = (int*)p; p += (size_t)T * 64 * 4 * Bc;
  float* val2 = (float*)p;

  // prep (once)
  cast_f32_bf16_k<<<2048, 256, 0, stream>>>(x, xb, BT * D);
  cast_f32_bf16_k<<<512, 256, 0, stream>>>(downW, dwb, (long long)N * D);
  cast_f32_bf16_k<<<128, 256, 0, stream>>>(gateW, gwb, (long long)D * D);
  transpose_upw_k<<<dim3(N / 32, D / 32), 256, 0, stream>>>(upW, upT, D, N);

  for (int b0 = 0; b0 < B; b0 += Bc) {
    const uint16_t* xc = xb + (long long)b0 * TD;
    // h = relu(x @ down_W^T) -> regA (bf16)
    gemm_bt_k<EPI_RELU_BF16, 0><<<dim3(Bc * 16, 16, 1), 256, 0, stream>>>(
        xc, dwb, regA, nullptr, Bc * T, N, D, 0, 0, 0);
    // S = l2norm(kwta(h)) -> regB (dense bf16)
    topk_bf16_k<0><<<Bc * T, 256, 0, stream>>>(regA, regB, nullptr, nullptr);
    // ST -> regA (h dead)
    transpose_k<<<dim3(T / 64, N / 64, Bc), 256, 0, stream>>>(regB, regA, T, N);
    // W[b] = shift(ST) @ ST^T, diag 0 -> regC (bf16)
    gemm_bt_k<EPI_DIAG0, 1><<<dim3(N / 128, N / 128, Bc), 256, 0, stream>>>(
        regA, regA, regC, nullptr, N, N, T, TN, TN, NN);
    // succ[b] = relu(S @ W^T) -> regA (ST dead)
    gemm_bt_k<EPI_RELU_BF16, 0><<<dim3(T / 128, N / 128, Bc), 256, 0, stream>>>(
        regB, regC, regA, nullptr, T, N, N, TN, NN, TN);
    // sparse l2norm(kwta(succ))
    topk_bf16_k<1><<<Bc * T, 256, 0, stream>>>(regA, nullptr, idx2, val2);
    // g = sigmoid(x @ gate_W^T + b) -> regB fp32 (S dead)
    gemm_bt_k<EPI_SIG, 0><<<dim3(Bc * 16, D / 128, 1), 256, 0, stream>>>(
        xc, gwb, regB, gateB, Bc * T, D, D, 0, 0, 0);
    // out = x + g * prediction
    final_k<<<Bc * T, 128, 0, stream>>>(x + (long long)b0 * TD, (const float*)regB,
                                        upT, idx2, val2, out + (long long)b0 * TD, D);
  }
}